// Round 1
// baseline (1080.136 us; speedup 1.0000x reference)
//
#include <hip/hip_runtime.h>
#include <math.h>

#define NB 4
#define NN 1024
#define NM 1024
#define NC 384
#define NK 10
#define NG 2
#define NGC 192
#define NH 6

__device__ __forceinline__ float wred_sum(float v) {
#pragma unroll
  for (int m = 32; m >= 1; m >>= 1) v += __shfl_xor(v, m, 64);
  return v;
}

// Wt[i][o] = W[o][i0+i]  (W is [384][384] row-major)
__global__ void transpose_slice_k(const float* __restrict__ W, int i0, int icount,
                                  float* __restrict__ Wt) {
  int id = blockIdx.x * blockDim.x + threadIdx.x;
  if (id >= icount * NC) return;
  int o = id % NC;
  int i = id / NC;
  Wt[(size_t)i * NC + o] = W[(size_t)o * NC + i0 + i];
}

// Wcomb_t[g][i][o] = sum_j Woff1[o][j] * Wvoff[g*192+j][i]   (j < 192)
__global__ void wcomb_k(const float* __restrict__ Woff1, const float* __restrict__ Wvoff,
                        float* __restrict__ Wcomb_t) {
  int o = blockIdx.x;
  int g = blockIdx.y;
  int i = threadIdx.x;
  __shared__ float w1[NGC];
  if (i < NGC) w1[i] = Woff1[(size_t)o * NC + i];
  __syncthreads();
  float acc = 0.f;
#pragma unroll 4
  for (int j = 0; j < NGC; ++j)
    acc = fmaf(w1[j], Wvoff[(size_t)(g * NGC + j) * NC + i], acc);
  Wcomb_t[((size_t)g * NC + i) * NC + o] = acc;
}

// Y[r][o] = sum_k X[r][xoff+k] * Wt[k][o] (+bias[o]); OUT = 384 fixed
template <int TR>
__global__ __launch_bounds__(NC) void linear_k(const float* __restrict__ X, int ldx, int xoff,
                                               int IN, const float* __restrict__ Wt,
                                               const float* __restrict__ bias,
                                               float* __restrict__ Y) {
  __shared__ float xs[TR][NC];
  int o = threadIdx.x;
  int r0 = blockIdx.x * TR;
  for (int t = threadIdx.x; t < TR * IN; t += NC) {
    int r = t / IN, kk = t % IN;
    xs[r][kk] = X[(size_t)(r0 + r) * ldx + xoff + kk];
  }
  __syncthreads();
  float acc[TR];
#pragma unroll
  for (int r = 0; r < TR; ++r) acc[r] = 0.f;
  for (int kk = 0; kk < IN; ++kk) {
    float w = Wt[(size_t)kk * NC + o];
#pragma unroll
    for (int r = 0; r < TR; ++r) acc[r] = fmaf(xs[r][kk], w, acc[r]);
  }
  float bv = bias ? bias[o] : 0.f;
#pragma unroll
  for (int r = 0; r < TR; ++r) Y[(size_t)(r0 + r) * NC + o] = acc[r] + bv;
}

__global__ __launch_bounds__(256) void knn_k(const float* __restrict__ q_pos,
                                             const float* __restrict__ v_pos,
                                             int* __restrict__ knn_idx) {
  __shared__ float px[NM], py[NM], pz[NM], ss[NM];
  int b = blockIdx.x / (NN / 256);
  int n = (blockIdx.x % (NN / 256)) * 256 + threadIdx.x;
  for (int t = threadIdx.x; t < NM; t += 256) {
    float x = v_pos[((size_t)b * NM + t) * 3 + 0];
    float y = v_pos[((size_t)b * NM + t) * 3 + 1];
    float z = v_pos[((size_t)b * NM + t) * 3 + 2];
    px[t] = x; py[t] = y; pz[t] = z;
    ss[t] = x * x + y * y + z * z;
  }
  __syncthreads();
  float qx = q_pos[((size_t)b * NN + n) * 3 + 0];
  float qy = q_pos[((size_t)b * NN + n) * 3 + 1];
  float qz = q_pos[((size_t)b * NN + n) * 3 + 2];
  float qq = qx * qx + qy * qy + qz * qz;
  float bd[NK];
  int bi[NK];
#pragma unroll
  for (int j = 0; j < NK; ++j) { bd[j] = 1e30f; bi[j] = 0; }
  for (int m = 0; m < NM; ++m) {
    float d = qq + ss[m] - 2.f * (qx * px[m] + qy * py[m] + qz * pz[m]);
    if (d < bd[NK - 1]) {
      bd[NK - 1] = d; bi[NK - 1] = m;
#pragma unroll
      for (int t = NK - 1; t > 0; --t) {
        if (bd[t] < bd[t - 1]) {
          float td = bd[t]; bd[t] = bd[t - 1]; bd[t - 1] = td;
          int ti = bi[t]; bi[t] = bi[t - 1]; bi[t - 1] = ti;
        }
      }
    }
  }
#pragma unroll
  for (int j = 0; j < NK; ++j) knn_idx[((size_t)b * NN + n) * NK + j] = bi[j];
}

// one wave per (b,g,n,k) row: h = vcontrib[m] + qcontrib[n] + boff1 -> LN -> GELU -> @Woff2 -> tanh -> +v_pos[m]
__global__ __launch_bounds__(256) void mlp_k(
    const float* __restrict__ vcontrib, const float* __restrict__ qcontrib,
    const float* __restrict__ boff1, const float* __restrict__ ln_g,
    const float* __restrict__ ln_b, const float* __restrict__ Woff2,
    const int* __restrict__ knn_idx, const float* __restrict__ v_pos,
    float* __restrict__ shift_pos) {
  int lane = threadIdx.x & 63;
  int r = blockIdx.x * 4 + (threadIdx.x >> 6);
  int k = r % NK;
  int n = (r / NK) % NN;
  int g = (r / (NK * NN)) % NG;
  int b = r / (NK * NN * NG);
  int m = knn_idx[((size_t)b * NN + n) * NK + k];
  const float* vc = vcontrib + ((size_t)(g * NB + b) * NM + m) * NC;
  const float* qc = qcontrib + ((size_t)(g * NB + b) * NN + n) * NC;
  float h[6];
  float s = 0.f, s2 = 0.f;
#pragma unroll
  for (int j = 0; j < 6; ++j) {
    int c = j * 64 + lane;
    float x = vc[c] + qc[c] + boff1[c];
    h[j] = x; s += x; s2 += x * x;
  }
  s = wred_sum(s);
  s2 = wred_sum(s2);
  float mean = s * (1.f / NC);
  float var = s2 * (1.f / NC) - mean * mean;
  float inv = 1.f / sqrtf(var + 1e-5f);
  float p0 = 0.f, p1 = 0.f, p2 = 0.f;
#pragma unroll
  for (int j = 0; j < 6; ++j) {
    int c = j * 64 + lane;
    float x = (h[j] - mean) * inv * ln_g[c] + ln_b[c];
    x = 0.5f * x * (1.f + erff(x * 0.70710678118654752f));
    p0 = fmaf(x, Woff2[0 * NC + c], p0);
    p1 = fmaf(x, Woff2[1 * NC + c], p1);
    p2 = fmaf(x, Woff2[2 * NC + c], p2);
  }
  p0 = wred_sum(p0);
  p1 = wred_sum(p1);
  p2 = wred_sum(p2);
  if (lane == 0) {
    const float* vp = v_pos + ((size_t)b * NM + m) * 3;
    shift_pos[(size_t)r * 3 + 0] = vp[0] + tanhf(p0);
    shift_pos[(size_t)r * 3 + 1] = vp[1] + tanhf(p1);
    shift_pos[(size_t)r * 3 + 2] = vp[2] + tanhf(p2);
  }
}

__global__ __launch_bounds__(256) void three_nn_k(const float* __restrict__ shift_pos,
                                                  const float* __restrict__ v_pos,
                                                  int* __restrict__ idx3,
                                                  float* __restrict__ w3) {
  __shared__ float px[NM], py[NM], pz[NM], ss[NM];
  int r = blockIdx.x * 256 + threadIdx.x;
  int b = r / (NG * NN * NK);
  for (int t = threadIdx.x; t < NM; t += 256) {
    float x = v_pos[((size_t)b * NM + t) * 3 + 0];
    float y = v_pos[((size_t)b * NM + t) * 3 + 1];
    float z = v_pos[((size_t)b * NM + t) * 3 + 2];
    px[t] = x; py[t] = y; pz[t] = z;
    ss[t] = x * x + y * y + z * z;
  }
  __syncthreads();
  float sx = shift_pos[(size_t)r * 3 + 0];
  float sy = shift_pos[(size_t)r * 3 + 1];
  float sz = shift_pos[(size_t)r * 3 + 2];
  float qq = sx * sx + sy * sy + sz * sz;
  float d0 = 1e30f, d1 = 1e30f, d2 = 1e30f;
  int i0 = 0, i1 = 0, i2 = 0;
  for (int m = 0; m < NM; ++m) {
    float d = qq + ss[m] - 2.f * (sx * px[m] + sy * py[m] + sz * pz[m]);
    if (d < d2) {
      d2 = d; i2 = m;
      if (d2 < d1) { float t = d1; d1 = d2; d2 = t; int ti = i1; i1 = i2; i2 = ti; }
      if (d1 < d0) { float t = d0; d0 = d1; d1 = t; int ti = i0; i0 = i1; i1 = ti; }
    }
  }
  float e0 = 1.f / (sqrtf(fmaxf(d0, 0.f)) + 1e-8f);
  float e1 = 1.f / (sqrtf(fmaxf(d1, 0.f)) + 1e-8f);
  float e2 = 1.f / (sqrtf(fmaxf(d2, 0.f)) + 1e-8f);
  float sw = e0 + e1 + e2;
  idx3[(size_t)r * 3 + 0] = i0; w3[(size_t)r * 3 + 0] = e0 / sw;
  idx3[(size_t)r * 3 + 1] = i1; w3[(size_t)r * 3 + 1] = e1 / sw;
  idx3[(size_t)r * 3 + 2] = i2; w3[(size_t)r * 3 + 2] = e2 / sw;
}

// one block per (b,n): kf/vf via 6-term gathered sums from Kc/Vc tables, then 6-head 10-way attention
__global__ __launch_bounds__(NC) void attn_k(const float* __restrict__ qp,
                                             const float* __restrict__ Kc,
                                             const float* __restrict__ Vc,
                                             const int* __restrict__ idx3,
                                             const float* __restrict__ w3,
                                             float* __restrict__ attn_out) {
  __shared__ float vfs[NK][NC];
  __shared__ float lgs[NH][NK];
  __shared__ int il[NG][NK][3];
  __shared__ float wl[NG][NK][3];
  int o = threadIdx.x;
  int lane = o & 63, wid = o >> 6;
  int b = blockIdx.x / NN;
  int n = blockIdx.x % NN;
  if (o < NG * NK * 3) {
    int g = o / (NK * 3), k = (o / 3) % NK, j = o % 3;
    size_t rr = (((size_t)(b * NG + g) * NN + n) * NK + k) * 3 + j;
    il[g][k][j] = idx3[rr];
    wl[g][k][j] = w3[rr];
  }
  __syncthreads();
  float qv = qp[((size_t)b * NN + n) * NC + o];
  for (int k = 0; k < NK; ++k) {
    float kf = 0.f, vf = 0.f;
#pragma unroll
    for (int g = 0; g < NG; ++g)
#pragma unroll
      for (int j = 0; j < 3; ++j) {
        int m = il[g][k][j];
        float w = wl[g][k][j];
        size_t base = ((size_t)(g * NB + b) * NM + m) * NC + o;
        kf = fmaf(w, Kc[base], kf);
        vf = fmaf(w, Vc[base], vf);
      }
    vfs[k][o] = vf;
    float p = wred_sum(qv * kf);
    if (lane == 0) lgs[wid][k] = p * 0.125f;
  }
  __syncthreads();
  float a[NK];
  float mx = -1e30f;
#pragma unroll
  for (int k = 0; k < NK; ++k) { a[k] = lgs[wid][k]; mx = fmaxf(mx, a[k]); }
  float sum = 0.f;
#pragma unroll
  for (int k = 0; k < NK; ++k) { a[k] = expf(a[k] - mx); sum += a[k]; }
  float outv = 0.f;
#pragma unroll
  for (int k = 0; k < NK; ++k) outv = fmaf(a[k] / sum, vfs[k][o], outv);
  attn_out[((size_t)b * NN + n) * NC + o] = outv;
}

extern "C" void kernel_launch(void* const* d_in, const int* in_sizes, int n_in,
                              void* d_out, int out_size, void* d_ws, size_t ws_size,
                              hipStream_t stream) {
  (void)in_sizes; (void)n_in; (void)out_size; (void)ws_size;
  const float* q     = (const float*)d_in[0];
  const float* q_pos = (const float*)d_in[1];
  const float* v     = (const float*)d_in[2];
  const float* v_pos = (const float*)d_in[3];
  const float* Wq    = (const float*)d_in[4];
  const float* Wk    = (const float*)d_in[5];
  const float* Wv    = (const float*)d_in[6];
  const float* Wvoff = (const float*)d_in[7];
  const float* Woff1 = (const float*)d_in[8];
  const float* boff1 = (const float*)d_in[9];
  const float* ln_g  = (const float*)d_in[10];
  const float* ln_b  = (const float*)d_in[11];
  const float* Woff2 = (const float*)d_in[12];
  const float* Wproj = (const float*)d_in[13];
  const float* bproj = (const float*)d_in[14];
  float* out = (float*)d_out;

  char* p = (char*)d_ws;
  auto alloc_f = [&](size_t n) { float* r = (float*)p; p += n * sizeof(float); return r; };
  auto alloc_i = [&](size_t n) { int* r = (int*)p; p += n * sizeof(int); return r; };

  float* qp        = alloc_f((size_t)NB * NN * NC);
  float* qcontrib  = alloc_f((size_t)NG * NB * NN * NC);
  float* vcontrib  = alloc_f((size_t)NG * NB * NM * NC);
  float* KcT       = alloc_f((size_t)NG * NB * NM * NC);
  float* VcT       = alloc_f((size_t)NG * NB * NM * NC);
  float* Wq_t      = alloc_f((size_t)NC * NC);
  float* W1b_t     = alloc_f((size_t)NGC * NC);
  float* Wk0_t     = alloc_f((size_t)NGC * NC);
  float* Wk1_t     = alloc_f((size_t)NGC * NC);
  float* Wv0_t     = alloc_f((size_t)NGC * NC);
  float* Wv1_t     = alloc_f((size_t)NGC * NC);
  float* Wproj_t   = alloc_f((size_t)NC * NC);
  float* Wcomb_t   = alloc_f((size_t)NG * NC * NC);
  float* shift_pos = alloc_f((size_t)NB * NG * NN * NK * 3);
  float* w3        = alloc_f((size_t)NB * NG * NN * NK * 3);
  int* knn_idx     = alloc_i((size_t)NB * NN * NK);
  int* idx3        = alloc_i((size_t)NB * NG * NN * NK * 3);
  float* attn_out  = vcontrib;  // vcontrib is dead after mlp_k; reuse

  int tgrid  = (NC * NC + 255) / 256;
  int tgrid2 = (NGC * NC + 255) / 256;
  transpose_slice_k<<<tgrid, 256, 0, stream>>>(Wq, 0, NC, Wq_t);
  transpose_slice_k<<<tgrid2, 256, 0, stream>>>(Woff1, NGC, NGC, W1b_t);
  transpose_slice_k<<<tgrid2, 256, 0, stream>>>(Wk, 0, NGC, Wk0_t);
  transpose_slice_k<<<tgrid2, 256, 0, stream>>>(Wk, NGC, NGC, Wk1_t);
  transpose_slice_k<<<tgrid2, 256, 0, stream>>>(Wv, 0, NGC, Wv0_t);
  transpose_slice_k<<<tgrid2, 256, 0, stream>>>(Wv, NGC, NGC, Wv1_t);
  transpose_slice_k<<<tgrid, 256, 0, stream>>>(Wproj, 0, NC, Wproj_t);
  wcomb_k<<<dim3(NC, NG), NC, 0, stream>>>(Woff1, Wvoff, Wcomb_t);

  linear_k<16><<<NB * NN / 16, NC, 0, stream>>>(q, NC, 0, NC, Wq_t, nullptr, qp);
  knn_k<<<NB * (NN / 256), 256, 0, stream>>>(q_pos, v_pos, knn_idx);

  for (int g = 0; g < NG; ++g) {
    linear_k<16><<<NB * NN / 16, NC, 0, stream>>>(qp, NC, g * NGC, NGC, W1b_t, nullptr,
                                                  qcontrib + (size_t)g * NB * NN * NC);
    linear_k<16><<<NB * NM / 16, NC, 0, stream>>>(v, NC, 0, NC, Wcomb_t + (size_t)g * NC * NC,
                                                  nullptr, vcontrib + (size_t)g * NB * NM * NC);
    linear_k<16><<<NB * NM / 16, NC, 0, stream>>>(v, NC, g * NGC, NGC, g ? Wk1_t : Wk0_t,
                                                  nullptr, KcT + (size_t)g * NB * NM * NC);
    linear_k<16><<<NB * NM / 16, NC, 0, stream>>>(v, NC, g * NGC, NGC, g ? Wv1_t : Wv0_t,
                                                  nullptr, VcT + (size_t)g * NB * NM * NC);
  }

  mlp_k<<<NB * NG * NN * NK / 4, 256, 0, stream>>>(vcontrib, qcontrib, boff1, ln_g, ln_b,
                                                   Woff2, knn_idx, v_pos, shift_pos);
  three_nn_k<<<NB * NG * NN * NK / 256, 256, 0, stream>>>(shift_pos, v_pos, idx3, w3);
  attn_k<<<NB * NN, NC, 0, stream>>>(qp, KcT, VcT, idx3, w3, attn_out);
  linear_k<16><<<NB * NN / 16, NC, 0, stream>>>(attn_out, NC, 0, NC, Wproj_t, bproj, out);
}

// Round 2
// 590.158 us; speedup vs baseline: 1.8302x; 1.8302x over previous
//
#include <hip/hip_runtime.h>
#include <math.h>

#define NB 4
#define NN 1024
#define NM 1024
#define NC 384
#define NK 10
#define NG 2
#define NGC 192
#define NH 6

__device__ __forceinline__ float wred_sum(float v) {
#pragma unroll
  for (int m = 32; m >= 1; m >>= 1) v += __shfl_xor(v, m, 64);
  return v;
}

// lexicographic (d, m) min across 64 lanes; ties -> lower m (matches top_k)
__device__ __forceinline__ void wred_argmin(float& d, int& m) {
#pragma unroll
  for (int off = 32; off >= 1; off >>= 1) {
    float od = __shfl_xor(d, off, 64);
    int om = __shfl_xor(m, off, 64);
    if (od < d || (od == d && om < m)) { d = od; m = om; }
  }
}

// Wt[i][o] = W[o][i0+i]  (W is [384][384] row-major)
__global__ void transpose_slice_k(const float* __restrict__ W, int i0, int icount,
                                  float* __restrict__ Wt) {
  int id = blockIdx.x * blockDim.x + threadIdx.x;
  if (id >= icount * NC) return;
  int o = id % NC;
  int i = id / NC;
  Wt[(size_t)i * NC + o] = W[(size_t)o * NC + i0 + i];
}

// Wcomb_t[g][i][o] = sum_j Woff1[o][j] * Wvoff[g*192+j][i]   (j < 192)
__global__ void wcomb_k(const float* __restrict__ Woff1, const float* __restrict__ Wvoff,
                        float* __restrict__ Wcomb_t) {
  int o = blockIdx.x;
  int g = blockIdx.y;
  int i = threadIdx.x;
  __shared__ float w1[NGC];
  if (i < NGC) w1[i] = Woff1[(size_t)o * NC + i];
  __syncthreads();
  float acc = 0.f;
#pragma unroll 4
  for (int j = 0; j < NGC; ++j)
    acc = fmaf(w1[j], Wvoff[(size_t)(g * NGC + j) * NC + i], acc);
  Wcomb_t[((size_t)g * NC + i) * NC + o] = acc;
}

// 4x4 register-blocked: Y[r][o] = sum_k X[r][xoff+k] * Wt[k][o] (+bias), 16 rows/block
__global__ __launch_bounds__(384) void linear2_k(const float* __restrict__ X, int ldx, int xoff,
                                                 int IN, const float* __restrict__ Wt,
                                                 const float* __restrict__ bias,
                                                 float* __restrict__ Y) {
  __shared__ __align__(16) float xs[NC][20];  // [k][row], pad 20: bank-spread + 16B-aligned rows
  int tid = threadIdx.x;
  int og = tid % 96, rg = tid / 96;
  int r0 = blockIdx.x * 16;
  for (int t = tid; t < 16 * IN; t += 384) {
    int r = t / IN, kk = t % IN;
    xs[kk][r] = X[(size_t)(r0 + r) * ldx + xoff + kk];
  }
  __syncthreads();
  float acc[4][4];
#pragma unroll
  for (int i = 0; i < 4; ++i)
#pragma unroll
    for (int j = 0; j < 4; ++j) acc[i][j] = 0.f;
  int o = og * 4;
#pragma unroll 4
  for (int kk = 0; kk < IN; ++kk) {
    float4 w4 = *(const float4*)&Wt[(size_t)kk * NC + o];
    float4 x4 = *(const float4*)&xs[kk][rg * 4];
    float xr[4] = {x4.x, x4.y, x4.z, x4.w};
    float wr[4] = {w4.x, w4.y, w4.z, w4.w};
#pragma unroll
    for (int ri = 0; ri < 4; ++ri)
#pragma unroll
      for (int oi = 0; oi < 4; ++oi) acc[ri][oi] = fmaf(xr[ri], wr[oi], acc[ri][oi]);
  }
  float4 bv = make_float4(0.f, 0.f, 0.f, 0.f);
  if (bias) bv = *(const float4*)&bias[o];
#pragma unroll
  for (int ri = 0; ri < 4; ++ri) {
    float4 ov;
    ov.x = acc[ri][0] + bv.x;
    ov.y = acc[ri][1] + bv.y;
    ov.z = acc[ri][2] + bv.z;
    ov.w = acc[ri][3] + bv.w;
    *(float4*)&Y[(size_t)(r0 + rg * 4 + ri) * NC + o] = ov;
  }
}

// wave-per-query KNN: lane scans 16 candidates -> register top-10 -> argmin-merge
__global__ __launch_bounds__(256) void knn2_k(const float* __restrict__ q_pos,
                                              const float* __restrict__ v_pos,
                                              int* __restrict__ knn_idx) {
  __shared__ float px[NM], py[NM], pz[NM], ss[NM];
  int tid = threadIdx.x, lane = tid & 63, wid = tid >> 6;
  int b = blockIdx.x / (NN / 4);
  int n = (blockIdx.x % (NN / 4)) * 4 + wid;
  for (int t = tid; t < NM; t += 256) {
    float x = v_pos[((size_t)b * NM + t) * 3 + 0];
    float y = v_pos[((size_t)b * NM + t) * 3 + 1];
    float z = v_pos[((size_t)b * NM + t) * 3 + 2];
    px[t] = x; py[t] = y; pz[t] = z;
    ss[t] = x * x + y * y + z * z;
  }
  __syncthreads();
  float qx = q_pos[((size_t)b * NN + n) * 3 + 0];
  float qy = q_pos[((size_t)b * NN + n) * 3 + 1];
  float qz = q_pos[((size_t)b * NN + n) * 3 + 2];
  float qq = qx * qx + qy * qy + qz * qz;
  float bd[NK];
  int bi[NK];
#pragma unroll
  for (int j = 0; j < NK; ++j) { bd[j] = 1e30f; bi[j] = 0x7fffffff; }
#pragma unroll
  for (int t = 0; t < NM / 64; ++t) {
    int m = t * 64 + lane;
    float d = qq + ss[m] - 2.f * (qx * px[m] + qy * py[m] + qz * pz[m]);
    if (d < bd[NK - 1]) {
#pragma unroll
      for (int j = NK - 1; j > 0; --j) {
        if (d < bd[j - 1]) { bd[j] = bd[j - 1]; bi[j] = bi[j - 1]; }
        else if (d < bd[j]) { bd[j] = d; bi[j] = m; }
      }
      if (d < bd[0]) { bd[0] = d; bi[0] = m; }
    }
  }
  size_t base = ((size_t)b * NN + n) * NK;
#pragma unroll
  for (int round = 0; round < NK; ++round) {
    float dh = bd[0];
    int mh = bi[0];
    wred_argmin(dh, mh);
    if (lane == 0) knn_idx[base + round] = mh;
    if (bi[0] == mh) {  // winner lane pops its head
#pragma unroll
      for (int j = 0; j < NK - 1; ++j) { bd[j] = bd[j + 1]; bi[j] = bi[j + 1]; }
      bd[NK - 1] = 1e30f; bi[NK - 1] = 0x7fffffff;
    }
  }
}

// fused: one wave per (b,g,n,k) row.
// h = vcontrib[m] + qcontrib[n] + boff1 -> LN -> GELU -> @Woff2 -> tanh -> shift_pos (regs)
// -> lane-parallel 3-NN over LDS-staged v_pos -> reciprocal-distance weights
__global__ __launch_bounds__(256) void mlp3nn_k(
    const float* __restrict__ vcontrib, const float* __restrict__ qcontrib,
    const float* __restrict__ boff1, const float* __restrict__ ln_g,
    const float* __restrict__ ln_b, const float* __restrict__ Woff2,
    const int* __restrict__ knn_idx, const float* __restrict__ v_pos,
    int* __restrict__ idx3, float* __restrict__ w3) {
  __shared__ float px[NM], py[NM], pz[NM], ss[NM];
  int tid = threadIdx.x, lane = tid & 63, wid = tid >> 6;
  int r = blockIdx.x * 4 + wid;
  int b = (blockIdx.x * 4) / (NK * NN * NG);  // uniform per block (20480 % 4 == 0)
  for (int t = tid; t < NM; t += 256) {
    float x = v_pos[((size_t)b * NM + t) * 3 + 0];
    float y = v_pos[((size_t)b * NM + t) * 3 + 1];
    float z = v_pos[((size_t)b * NM + t) * 3 + 2];
    px[t] = x; py[t] = y; pz[t] = z;
    ss[t] = x * x + y * y + z * z;
  }
  __syncthreads();
  int k = r % NK;
  int n = (r / NK) % NN;
  int g = (r / (NK * NN)) % NG;
  int m = knn_idx[((size_t)b * NN + n) * NK + k];
  const float* vc = vcontrib + ((size_t)(g * NB + b) * NM + m) * NC;
  const float* qc = qcontrib + ((size_t)(g * NB + b) * NN + n) * NC;
  float h[6];
  float s = 0.f, s2 = 0.f;
#pragma unroll
  for (int j = 0; j < 6; ++j) {
    int c = j * 64 + lane;
    float x = vc[c] + qc[c] + boff1[c];
    h[j] = x; s += x; s2 += x * x;
  }
  s = wred_sum(s);
  s2 = wred_sum(s2);
  float mean = s * (1.f / NC);
  float var = s2 * (1.f / NC) - mean * mean;
  float inv = 1.f / sqrtf(var + 1e-5f);
  float p0 = 0.f, p1 = 0.f, p2 = 0.f;
#pragma unroll
  for (int j = 0; j < 6; ++j) {
    int c = j * 64 + lane;
    float x = (h[j] - mean) * inv * ln_g[c] + ln_b[c];
    x = 0.5f * x * (1.f + erff(x * 0.70710678118654752f));
    p0 = fmaf(x, Woff2[0 * NC + c], p0);
    p1 = fmaf(x, Woff2[1 * NC + c], p1);
    p2 = fmaf(x, Woff2[2 * NC + c], p2);
  }
  p0 = wred_sum(p0);
  p1 = wred_sum(p1);
  p2 = wred_sum(p2);
  // shift_pos on all lanes (butterfly reduce is all-lane)
  float sx = px[m] + tanhf(p0);
  float sy = py[m] + tanhf(p1);
  float sz = pz[m] + tanhf(p2);
  float qq2 = sx * sx + sy * sy + sz * sz;
  // lane-parallel 3-NN
  float d0v = 1e30f, d1v = 1e30f, d2v = 1e30f;
  int i0v = 0x7fffffff, i1v = 0x7fffffff, i2v = 0x7fffffff;
#pragma unroll
  for (int t = 0; t < NM / 64; ++t) {
    int m2 = t * 64 + lane;
    float d = qq2 + ss[m2] - 2.f * (sx * px[m2] + sy * py[m2] + sz * pz[m2]);
    if (d < d2v) {
      d2v = d; i2v = m2;
      if (d2v < d1v) { float td = d1v; d1v = d2v; d2v = td; int ti = i1v; i1v = i2v; i2v = ti; }
      if (d1v < d0v) { float td = d0v; d0v = d1v; d1v = td; int ti = i0v; i0v = i1v; i1v = ti; }
    }
  }
  float rd[3];
  int rm[3];
#pragma unroll
  for (int round = 0; round < 3; ++round) {
    float dh = d0v;
    int mh = i0v;
    wred_argmin(dh, mh);
    rd[round] = dh; rm[round] = mh;
    if (i0v == mh) {  // winner lane pops
      d0v = d1v; i0v = i1v;
      d1v = d2v; i1v = i2v;
      d2v = 1e30f; i2v = 0x7fffffff;
    }
  }
  if (lane == 0) {
    float e0 = 1.f / (sqrtf(fmaxf(rd[0], 0.f)) + 1e-8f);
    float e1 = 1.f / (sqrtf(fmaxf(rd[1], 0.f)) + 1e-8f);
    float e2 = 1.f / (sqrtf(fmaxf(rd[2], 0.f)) + 1e-8f);
    float sw = e0 + e1 + e2;
    idx3[(size_t)r * 3 + 0] = rm[0]; w3[(size_t)r * 3 + 0] = e0 / sw;
    idx3[(size_t)r * 3 + 1] = rm[1]; w3[(size_t)r * 3 + 1] = e1 / sw;
    idx3[(size_t)r * 3 + 2] = rm[2]; w3[(size_t)r * 3 + 2] = e2 / sw;
  }
}

// one block per (b,n): kf/vf via 6-term gathered sums from Kc/Vc tables, then 6-head 10-way attention
__global__ __launch_bounds__(NC) void attn_k(const float* __restrict__ qp,
                                             const float* __restrict__ Kc,
                                             const float* __restrict__ Vc,
                                             const int* __restrict__ idx3,
                                             const float* __restrict__ w3,
                                             float* __restrict__ attn_out) {
  __shared__ float vfs[NK][NC];
  __shared__ float lgs[NH][NK];
  __shared__ int il[NG][NK][3];
  __shared__ float wl[NG][NK][3];
  int o = threadIdx.x;
  int lane = o & 63, wid = o >> 6;
  int b = blockIdx.x / NN;
  int n = blockIdx.x % NN;
  if (o < NG * NK * 3) {
    int g = o / (NK * 3), k = (o / 3) % NK, j = o % 3;
    size_t rr = (((size_t)(b * NG + g) * NN + n) * NK + k) * 3 + j;
    il[g][k][j] = idx3[rr];
    wl[g][k][j] = w3[rr];
  }
  __syncthreads();
  float qv = qp[((size_t)b * NN + n) * NC + o];
  for (int k = 0; k < NK; ++k) {
    float kf = 0.f, vf = 0.f;
#pragma unroll
    for (int g = 0; g < NG; ++g)
#pragma unroll
      for (int j = 0; j < 3; ++j) {
        int m = il[g][k][j];
        float w = wl[g][k][j];
        size_t base = ((size_t)(g * NB + b) * NM + m) * NC + o;
        kf = fmaf(w, Kc[base], kf);
        vf = fmaf(w, Vc[base], vf);
      }
    vfs[k][o] = vf;
    float p = wred_sum(qv * kf);
    if (lane == 0) lgs[wid][k] = p * 0.125f;
  }
  __syncthreads();
  float a[NK];
  float mx = -1e30f;
#pragma unroll
  for (int k = 0; k < NK; ++k) { a[k] = lgs[wid][k]; mx = fmaxf(mx, a[k]); }
  float sum = 0.f;
#pragma unroll
  for (int k = 0; k < NK; ++k) { a[k] = expf(a[k] - mx); sum += a[k]; }
  float outv = 0.f;
#pragma unroll
  for (int k = 0; k < NK; ++k) outv = fmaf(a[k] / sum, vfs[k][o], outv);
  attn_out[((size_t)b * NN + n) * NC + o] = outv;
}

extern "C" void kernel_launch(void* const* d_in, const int* in_sizes, int n_in,
                              void* d_out, int out_size, void* d_ws, size_t ws_size,
                              hipStream_t stream) {
  (void)in_sizes; (void)n_in; (void)out_size; (void)ws_size;
  const float* q     = (const float*)d_in[0];
  const float* q_pos = (const float*)d_in[1];
  const float* v     = (const float*)d_in[2];
  const float* v_pos = (const float*)d_in[3];
  const float* Wq    = (const float*)d_in[4];
  const float* Wk    = (const float*)d_in[5];
  const float* Wv    = (const float*)d_in[6];
  const float* Wvoff = (const float*)d_in[7];
  const float* Woff1 = (const float*)d_in[8];
  const float* boff1 = (const float*)d_in[9];
  const float* ln_g  = (const float*)d_in[10];
  const float* ln_b  = (const float*)d_in[11];
  const float* Woff2 = (const float*)d_in[12];
  const float* Wproj = (const float*)d_in[13];
  const float* bproj = (const float*)d_in[14];
  float* out = (float*)d_out;

  char* p = (char*)d_ws;
  auto alloc_f = [&](size_t n) { float* r = (float*)p; p += n * sizeof(float); return r; };
  auto alloc_i = [&](size_t n) { int* r = (int*)p; p += n * sizeof(int); return r; };

  float* qp        = alloc_f((size_t)NB * NN * NC);
  float* qcontrib  = alloc_f((size_t)NG * NB * NN * NC);
  float* vcontrib  = alloc_f((size_t)NG * NB * NM * NC);
  float* KcT       = alloc_f((size_t)NG * NB * NM * NC);
  float* VcT       = alloc_f((size_t)NG * NB * NM * NC);
  float* Wq_t      = alloc_f((size_t)NC * NC);
  float* W1b_t     = alloc_f((size_t)NGC * NC);
  float* Wk0_t     = alloc_f((size_t)NGC * NC);
  float* Wk1_t     = alloc_f((size_t)NGC * NC);
  float* Wv0_t     = alloc_f((size_t)NGC * NC);
  float* Wv1_t     = alloc_f((size_t)NGC * NC);
  float* Wproj_t   = alloc_f((size_t)NC * NC);
  float* Wcomb_t   = alloc_f((size_t)NG * NC * NC);
  float* w3        = alloc_f((size_t)NB * NG * NN * NK * 3);
  int* knn_idx     = alloc_i((size_t)NB * NN * NK);
  int* idx3        = alloc_i((size_t)NB * NG * NN * NK * 3);
  float* attn_out  = vcontrib;  // vcontrib dead after mlp3nn_k; reuse

  int tgrid  = (NC * NC + 255) / 256;
  int tgrid2 = (NGC * NC + 255) / 256;
  transpose_slice_k<<<tgrid, 256, 0, stream>>>(Wq, 0, NC, Wq_t);
  transpose_slice_k<<<tgrid2, 256, 0, stream>>>(Woff1, NGC, NGC, W1b_t);
  transpose_slice_k<<<tgrid2, 256, 0, stream>>>(Wk, 0, NGC, Wk0_t);
  transpose_slice_k<<<tgrid2, 256, 0, stream>>>(Wk, NGC, NGC, Wk1_t);
  transpose_slice_k<<<tgrid2, 256, 0, stream>>>(Wv, 0, NGC, Wv0_t);
  transpose_slice_k<<<tgrid2, 256, 0, stream>>>(Wv, NGC, NGC, Wv1_t);
  transpose_slice_k<<<tgrid, 256, 0, stream>>>(Wproj, 0, NC, Wproj_t);
  wcomb_k<<<dim3(NC, NG), NC, 0, stream>>>(Woff1, Wvoff, Wcomb_t);

  linear2_k<<<NB * NN / 16, 384, 0, stream>>>(q, NC, 0, NC, Wq_t, nullptr, qp);
  knn2_k<<<NB * (NN / 4), 256, 0, stream>>>(q_pos, v_pos, knn_idx);

  for (int g = 0; g < NG; ++g) {
    linear2_k<<<NB * NN / 16, 384, 0, stream>>>(qp, NC, g * NGC, NGC, W1b_t, nullptr,
                                                qcontrib + (size_t)g * NB * NN * NC);
    linear2_k<<<NB * NM / 16, 384, 0, stream>>>(v, NC, 0, NC, Wcomb_t + (size_t)g * NC * NC,
                                                nullptr, vcontrib + (size_t)g * NB * NM * NC);
    linear2_k<<<NB * NM / 16, 384, 0, stream>>>(v, NC, g * NGC, NGC, g ? Wk1_t : Wk0_t,
                                                nullptr, KcT + (size_t)g * NB * NM * NC);
    linear2_k<<<NB * NM / 16, 384, 0, stream>>>(v, NC, g * NGC, NGC, g ? Wv1_t : Wv0_t,
                                                nullptr, VcT + (size_t)g * NB * NM * NC);
  }

  mlp3nn_k<<<NB * NG * NN * NK / 4, 256, 0, stream>>>(vcontrib, qcontrib, boff1, ln_g, ln_b,
                                                      Woff2, knn_idx, v_pos, idx3, w3);
  attn_k<<<NB * NN, NC, 0, stream>>>(qp, KcT, VcT, idx3, w3, attn_out);
  linear2_k<<<NB * NN / 16, 384, 0, stream>>>(attn_out, NC, 0, NC, Wproj_t, bproj, out);
}

// Round 3
// 543.341 us; speedup vs baseline: 1.9880x; 1.0862x over previous
//
#include <hip/hip_runtime.h>
#include <math.h>

#define NB 4
#define NN 1024
#define NM 1024
#define NC 384
#define NK 10
#define NG 2
#define NGC 192
#define NH 6

#define GSZ ((size_t)NB * NM * NC)  // per-g table size (floats)

// Wt_all layout (floats)
#define OFF_WQ 0
#define OFF_W1B 147456
#define OFF_WK0 221184
#define OFF_WK1 294912
#define OFF_WV0 368640
#define OFF_WV1 442368
#define OFF_WPROJ 516096
#define WT_ALL_FLOATS 663552

__device__ __forceinline__ float wred_sum(float v) {
#pragma unroll
  for (int m = 32; m >= 1; m >>= 1) v += __shfl_xor(v, m, 64);
  return v;
}

// lexicographic (d, m) min across 64 lanes; ties -> lower m (matches top_k)
__device__ __forceinline__ void wred_argmin(float& d, int& m) {
#pragma unroll
  for (int off = 32; off >= 1; off >>= 1) {
    float od = __shfl_xor(d, off, 64);
    int om = __shfl_xor(m, off, 64);
    if (od < d || (od == d && om < m)) { d = od; m = om; }
  }
}

// all 7 weight transposes in one launch; blockIdx.y = job
__global__ void transpose_all_k(const float* __restrict__ Wq, const float* __restrict__ Woff1,
                                const float* __restrict__ Wk, const float* __restrict__ Wv,
                                const float* __restrict__ Wproj, float* __restrict__ Wt_all) {
  const float* W;
  int i0, icount, doff;
  switch (blockIdx.y) {
    case 0: W = Wq;    i0 = 0;   icount = NC;  doff = OFF_WQ;    break;
    case 1: W = Woff1; i0 = NGC; icount = NGC; doff = OFF_W1B;   break;
    case 2: W = Wk;    i0 = 0;   icount = NGC; doff = OFF_WK0;   break;
    case 3: W = Wk;    i0 = NGC; icount = NGC; doff = OFF_WK1;   break;
    case 4: W = Wv;    i0 = 0;   icount = NGC; doff = OFF_WV0;   break;
    case 5: W = Wv;    i0 = NGC; icount = NGC; doff = OFF_WV1;   break;
    default: W = Wproj; i0 = 0;  icount = NC;  doff = OFF_WPROJ; break;
  }
  int id = blockIdx.x * 256 + threadIdx.x;
  if (id >= icount * NC) return;
  int o = id % NC;
  int i = id / NC;
  Wt_all[doff + (size_t)i * NC + o] = W[(size_t)o * NC + i0 + i];
}

// Wcomb_t[g][i][o] = sum_j Woff1[o][j] * Wvoff[g*192+j][i]   (j < 192)
__global__ void wcomb_k(const float* __restrict__ Woff1, const float* __restrict__ Wvoff,
                        float* __restrict__ Wcomb_t) {
  int o = blockIdx.x;
  int g = blockIdx.y;
  int i = threadIdx.x;
  __shared__ float w1[NGC];
  if (i < NGC) w1[i] = Woff1[(size_t)o * NC + i];
  __syncthreads();
  float acc = 0.f;
#pragma unroll 4
  for (int j = 0; j < NGC; ++j)
    acc = fmaf(w1[j], Wvoff[(size_t)(g * NGC + j) * NC + i], acc);
  Wcomb_t[((size_t)g * NC + i) * NC + o] = acc;
}

// 4x4 register-blocked single GEMM: Y[r][o] = sum_k X[r][k] * Wt[k][o] (+bias)
__global__ __launch_bounds__(384) void linear2_k(const float* __restrict__ X, int IN,
                                                 const float* __restrict__ Wt,
                                                 const float* __restrict__ bias,
                                                 float* __restrict__ Y) {
  __shared__ __align__(16) float xs[NC][20];
  int tid = threadIdx.x;
  int og = tid % 96, rg = tid / 96;
  int r0 = blockIdx.x * 16;
  for (int t = tid; t < 16 * IN; t += 384) {
    int r = t / IN, kk = t % IN;
    xs[kk][r] = X[(size_t)(r0 + r) * NC + kk];
  }
  __syncthreads();
  float acc[4][4];
#pragma unroll
  for (int i = 0; i < 4; ++i)
#pragma unroll
    for (int j = 0; j < 4; ++j) acc[i][j] = 0.f;
  int o = og * 4;
#pragma unroll 4
  for (int kk = 0; kk < IN; ++kk) {
    float4 w4 = *(const float4*)&Wt[(size_t)kk * NC + o];
    float4 x4 = *(const float4*)&xs[kk][rg * 4];
    float xr[4] = {x4.x, x4.y, x4.z, x4.w};
    float wr[4] = {w4.x, w4.y, w4.z, w4.w};
#pragma unroll
    for (int ri = 0; ri < 4; ++ri)
#pragma unroll
      for (int oi = 0; oi < 4; ++oi) acc[ri][oi] = fmaf(xr[ri], wr[oi], acc[ri][oi]);
  }
  float4 bv = make_float4(0.f, 0.f, 0.f, 0.f);
  if (bias) bv = *(const float4*)&bias[o];
#pragma unroll
  for (int ri = 0; ri < 4; ++ri) {
    float4 ov;
    ov.x = acc[ri][0] + bv.x;
    ov.y = acc[ri][1] + bv.y;
    ov.z = acc[ri][2] + bv.z;
    ov.w = acc[ri][3] + bv.w;
    *(float4*)&Y[(size_t)(r0 + rg * 4 + ri) * NC + o] = ov;
  }
}

// fused v projections: stage 16 v-rows once, run 6 GEMMs:
// vcontrib g0/g1 (IN=384, Wcomb), Kc g0/g1, Vc g0/g1 (IN=192 slices)
__global__ __launch_bounds__(384) void vproj_k(const float* __restrict__ v,
                                               const float* __restrict__ Wcomb_t,
                                               const float* __restrict__ Wt_all,
                                               float* __restrict__ vcontrib,
                                               float* __restrict__ KcT,
                                               float* __restrict__ VcT) {
  __shared__ __align__(16) float xs[NC][20];
  int tid = threadIdx.x;
  int og = tid % 96, rg = tid / 96;
  int r0 = blockIdx.x * 16;
  for (int t = tid; t < 16 * NC; t += 384) {
    int r = t / NC, kk = t % NC;
    xs[kk][r] = v[(size_t)(r0 + r) * NC + kk];
  }
  __syncthreads();
  const float* Wj[6] = {Wcomb_t,           Wcomb_t + (size_t)NC * NC,
                        Wt_all + OFF_WK0,  Wt_all + OFF_WK1,
                        Wt_all + OFF_WV0,  Wt_all + OFF_WV1};
  float* Yj[6] = {vcontrib, vcontrib + GSZ, KcT, KcT + GSZ, VcT, VcT + GSZ};
  const int inj[6] = {NC, NC, NGC, NGC, NGC, NGC};
  const int xoj[6] = {0, 0, 0, NGC, 0, NGC};
  int o = og * 4;
#pragma unroll
  for (int job = 0; job < 6; ++job) {
    const float* Wt = Wj[job];
    float* Y = Yj[job];
    const int IN = inj[job], xoff = xoj[job];
    float acc[4][4];
#pragma unroll
    for (int i = 0; i < 4; ++i)
#pragma unroll
      for (int j = 0; j < 4; ++j) acc[i][j] = 0.f;
#pragma unroll 4
    for (int kk = 0; kk < IN; ++kk) {
      float4 w4 = *(const float4*)&Wt[(size_t)kk * NC + o];
      float4 x4 = *(const float4*)&xs[xoff + kk][rg * 4];
      float xr[4] = {x4.x, x4.y, x4.z, x4.w};
      float wr[4] = {w4.x, w4.y, w4.z, w4.w};
#pragma unroll
      for (int ri = 0; ri < 4; ++ri)
#pragma unroll
        for (int oi = 0; oi < 4; ++oi) acc[ri][oi] = fmaf(xr[ri], wr[oi], acc[ri][oi]);
    }
#pragma unroll
    for (int ri = 0; ri < 4; ++ri)
      *(float4*)&Y[(size_t)(r0 + rg * 4 + ri) * NC + o] =
          make_float4(acc[ri][0], acc[ri][1], acc[ri][2], acc[ri][3]);
  }
}

// fused q projections: qp = q@Wq^T (written out), then qp re-staged in the SAME LDS
// buffer -> qcontrib g0/g1 = qp_slice @ W1b
__global__ __launch_bounds__(384) void qproj_k(const float* __restrict__ q,
                                               const float* __restrict__ Wt_all,
                                               float* __restrict__ qp,
                                               float* __restrict__ qcontrib) {
  __shared__ __align__(16) float xs[NC][20];
  int tid = threadIdx.x;
  int og = tid % 96, rg = tid / 96;
  int r0 = blockIdx.x * 16;
  for (int t = tid; t < 16 * NC; t += 384) {
    int r = t / NC, kk = t % NC;
    xs[kk][r] = q[(size_t)(r0 + r) * NC + kk];
  }
  __syncthreads();
  int o = og * 4;
  const float* Wqt = Wt_all + OFF_WQ;
  float acc[4][4];
#pragma unroll
  for (int i = 0; i < 4; ++i)
#pragma unroll
    for (int j = 0; j < 4; ++j) acc[i][j] = 0.f;
#pragma unroll 4
  for (int kk = 0; kk < NC; ++kk) {
    float4 w4 = *(const float4*)&Wqt[(size_t)kk * NC + o];
    float4 x4 = *(const float4*)&xs[kk][rg * 4];
    float xr[4] = {x4.x, x4.y, x4.z, x4.w};
    float wr[4] = {w4.x, w4.y, w4.z, w4.w};
#pragma unroll
    for (int ri = 0; ri < 4; ++ri)
#pragma unroll
      for (int oi = 0; oi < 4; ++oi) acc[ri][oi] = fmaf(xr[ri], wr[oi], acc[ri][oi]);
  }
#pragma unroll
  for (int ri = 0; ri < 4; ++ri)
    *(float4*)&qp[(size_t)(r0 + rg * 4 + ri) * NC + o] =
        make_float4(acc[ri][0], acc[ri][1], acc[ri][2], acc[ri][3]);
  __syncthreads();  // all reads of q-tile done
#pragma unroll
  for (int ri = 0; ri < 4; ++ri)
#pragma unroll
    for (int oi = 0; oi < 4; ++oi) xs[o + oi][rg * 4 + ri] = acc[ri][oi];
  __syncthreads();  // qp tile staged
  const float* W1b = Wt_all + OFF_W1B;
#pragma unroll
  for (int g = 0; g < NG; ++g) {
    float a2[4][4];
#pragma unroll
    for (int i = 0; i < 4; ++i)
#pragma unroll
      for (int j = 0; j < 4; ++j) a2[i][j] = 0.f;
#pragma unroll 4
    for (int kk = 0; kk < NGC; ++kk) {
      float4 w4 = *(const float4*)&W1b[(size_t)kk * NC + o];
      float4 x4 = *(const float4*)&xs[g * NGC + kk][rg * 4];
      float xr[4] = {x4.x, x4.y, x4.z, x4.w};
      float wr[4] = {w4.x, w4.y, w4.z, w4.w};
#pragma unroll
      for (int ri = 0; ri < 4; ++ri)
#pragma unroll
        for (int oi = 0; oi < 4; ++oi) a2[ri][oi] = fmaf(xr[ri], wr[oi], a2[ri][oi]);
    }
    float* Yg = qcontrib + (size_t)g * NB * NN * NC;
#pragma unroll
    for (int ri = 0; ri < 4; ++ri)
      *(float4*)&Yg[(size_t)(r0 + rg * 4 + ri) * NC + o] =
          make_float4(a2[ri][0], a2[ri][1], a2[ri][2], a2[ri][3]);
  }
}

// wave-per-query KNN: lane scans 16 candidates -> register top-10 -> argmin-merge
__global__ __launch_bounds__(256) void knn2_k(const float* __restrict__ q_pos,
                                              const float* __restrict__ v_pos,
                                              int* __restrict__ knn_idx) {
  __shared__ float px[NM], py[NM], pz[NM], ss[NM];
  int tid = threadIdx.x, lane = tid & 63, wid = tid >> 6;
  int b = blockIdx.x / (NN / 4);
  int n = (blockIdx.x % (NN / 4)) * 4 + wid;
  for (int t = tid; t < NM; t += 256) {
    float x = v_pos[((size_t)b * NM + t) * 3 + 0];
    float y = v_pos[((size_t)b * NM + t) * 3 + 1];
    float z = v_pos[((size_t)b * NM + t) * 3 + 2];
    px[t] = x; py[t] = y; pz[t] = z;
    ss[t] = x * x + y * y + z * z;
  }
  __syncthreads();
  float qx = q_pos[((size_t)b * NN + n) * 3 + 0];
  float qy = q_pos[((size_t)b * NN + n) * 3 + 1];
  float qz = q_pos[((size_t)b * NN + n) * 3 + 2];
  float qq = qx * qx + qy * qy + qz * qz;
  float bd[NK];
  int bi[NK];
#pragma unroll
  for (int j = 0; j < NK; ++j) { bd[j] = 1e30f; bi[j] = 0x7fffffff; }
#pragma unroll
  for (int t = 0; t < NM / 64; ++t) {
    int m = t * 64 + lane;
    float d = qq + ss[m] - 2.f * (qx * px[m] + qy * py[m] + qz * pz[m]);
    if (d < bd[NK - 1]) {
#pragma unroll
      for (int j = NK - 1; j > 0; --j) {
        if (d < bd[j - 1]) { bd[j] = bd[j - 1]; bi[j] = bi[j - 1]; }
        else if (d < bd[j]) { bd[j] = d; bi[j] = m; }
      }
      if (d < bd[0]) { bd[0] = d; bi[0] = m; }
    }
  }
  size_t base = ((size_t)b * NN + n) * NK;
#pragma unroll
  for (int round = 0; round < NK; ++round) {
    float dh = bd[0];
    int mh = bi[0];
    wred_argmin(dh, mh);
    if (lane == 0) knn_idx[base + round] = mh;
    if (bi[0] == mh) {
#pragma unroll
      for (int j = 0; j < NK - 1; ++j) { bd[j] = bd[j + 1]; bi[j] = bi[j + 1]; }
      bd[NK - 1] = 1e30f; bi[NK - 1] = 0x7fffffff;
    }
  }
}

// fused MLP + three_nn: one wave per (b,g,n,k) row
__global__ __launch_bounds__(256) void mlp3nn_k(
    const float* __restrict__ vcontrib, const float* __restrict__ qcontrib,
    const float* __restrict__ boff1, const float* __restrict__ ln_g,
    const float* __restrict__ ln_b, const float* __restrict__ Woff2,
    const int* __restrict__ knn_idx, const float* __restrict__ v_pos,
    int* __restrict__ idx3, float* __restrict__ w3) {
  __shared__ float px[NM], py[NM], pz[NM], ss[NM];
  int tid = threadIdx.x, lane = tid & 63, wid = tid >> 6;
  int r = blockIdx.x * 4 + wid;
  int b = (blockIdx.x * 4) / (NK * NN * NG);
  for (int t = tid; t < NM; t += 256) {
    float x = v_pos[((size_t)b * NM + t) * 3 + 0];
    float y = v_pos[((size_t)b * NM + t) * 3 + 1];
    float z = v_pos[((size_t)b * NM + t) * 3 + 2];
    px[t] = x; py[t] = y; pz[t] = z;
    ss[t] = x * x + y * y + z * z;
  }
  __syncthreads();
  int k = r % NK;
  int n = (r / NK) % NN;
  int g = (r / (NK * NN)) % NG;
  int m = knn_idx[((size_t)b * NN + n) * NK + k];
  const float* vc = vcontrib + ((size_t)(g * NB + b) * NM + m) * NC;
  const float* qc = qcontrib + ((size_t)(g * NB + b) * NN + n) * NC;
  float h[6];
  float s = 0.f, s2 = 0.f;
#pragma unroll
  for (int j = 0; j < 6; ++j) {
    int c = j * 64 + lane;
    float x = vc[c] + qc[c] + boff1[c];
    h[j] = x; s += x; s2 += x * x;
  }
  s = wred_sum(s);
  s2 = wred_sum(s2);
  float mean = s * (1.f / NC);
  float var = s2 * (1.f / NC) - mean * mean;
  float inv = 1.f / sqrtf(var + 1e-5f);
  float p0 = 0.f, p1 = 0.f, p2 = 0.f;
#pragma unroll
  for (int j = 0; j < 6; ++j) {
    int c = j * 64 + lane;
    float x = (h[j] - mean) * inv * ln_g[c] + ln_b[c];
    x = 0.5f * x * (1.f + erff(x * 0.70710678118654752f));
    p0 = fmaf(x, Woff2[0 * NC + c], p0);
    p1 = fmaf(x, Woff2[1 * NC + c], p1);
    p2 = fmaf(x, Woff2[2 * NC + c], p2);
  }
  p0 = wred_sum(p0);
  p1 = wred_sum(p1);
  p2 = wred_sum(p2);
  float sx = px[m] + tanhf(p0);
  float sy = py[m] + tanhf(p1);
  float sz = pz[m] + tanhf(p2);
  float qq2 = sx * sx + sy * sy + sz * sz;
  float d0v = 1e30f, d1v = 1e30f, d2v = 1e30f;
  int i0v = 0x7fffffff, i1v = 0x7fffffff, i2v = 0x7fffffff;
#pragma unroll
  for (int t = 0; t < NM / 64; ++t) {
    int m2 = t * 64 + lane;
    float d = qq2 + ss[m2] - 2.f * (sx * px[m2] + sy * py[m2] + sz * pz[m2]);
    if (d < d2v) {
      d2v = d; i2v = m2;
      if (d2v < d1v) { float td = d1v; d1v = d2v; d2v = td; int ti = i1v; i1v = i2v; i2v = ti; }
      if (d1v < d0v) { float td = d0v; d0v = d1v; d1v = td; int ti = i0v; i0v = i1v; i1v = ti; }
    }
  }
  float rd[3];
  int rm[3];
#pragma unroll
  for (int round = 0; round < 3; ++round) {
    float dh = d0v;
    int mh = i0v;
    wred_argmin(dh, mh);
    rd[round] = dh; rm[round] = mh;
    if (i0v == mh) {
      d0v = d1v; i0v = i1v;
      d1v = d2v; i1v = i2v;
      d2v = 1e30f; i2v = 0x7fffffff;
    }
  }
  if (lane == 0) {
    float e0 = 1.f / (sqrtf(fmaxf(rd[0], 0.f)) + 1e-8f);
    float e1 = 1.f / (sqrtf(fmaxf(rd[1], 0.f)) + 1e-8f);
    float e2 = 1.f / (sqrtf(fmaxf(rd[2], 0.f)) + 1e-8f);
    float sw = e0 + e1 + e2;
    idx3[(size_t)r * 3 + 0] = rm[0]; w3[(size_t)r * 3 + 0] = e0 / sw;
    idx3[(size_t)r * 3 + 1] = rm[1]; w3[(size_t)r * 3 + 1] = e1 / sw;
    idx3[(size_t)r * 3 + 2] = rm[2]; w3[(size_t)r * 3 + 2] = e2 / sw;
  }
}

// one block per (b,n): kf/vf via 6-term gathered sums from Kc/Vc tables, then 6-head 10-way attention
__global__ __launch_bounds__(NC) void attn_k(const float* __restrict__ qp,
                                             const float* __restrict__ Kc,
                                             const float* __restrict__ Vc,
                                             const int* __restrict__ idx3,
                                             const float* __restrict__ w3,
                                             float* __restrict__ attn_out) {
  __shared__ float vfs[NK][NC];
  __shared__ float lgs[NH][NK];
  __shared__ int il[NG][NK][3];
  __shared__ float wl[NG][NK][3];
  int o = threadIdx.x;
  int lane = o & 63, wid = o >> 6;
  int b = blockIdx.x / NN;
  int n = blockIdx.x % NN;
  if (o < NG * NK * 3) {
    int g = o / (NK * 3), k = (o / 3) % NK, j = o % 3;
    size_t rr = (((size_t)(b * NG + g) * NN + n) * NK + k) * 3 + j;
    il[g][k][j] = idx3[rr];
    wl[g][k][j] = w3[rr];
  }
  __syncthreads();
  float qv = qp[((size_t)b * NN + n) * NC + o];
  for (int k = 0; k < NK; ++k) {
    float kf = 0.f, vf = 0.f;
#pragma unroll
    for (int g = 0; g < NG; ++g)
#pragma unroll
      for (int j = 0; j < 3; ++j) {
        int m = il[g][k][j];
        float w = wl[g][k][j];
        size_t base = ((size_t)(g * NB + b) * NM + m) * NC + o;
        kf = fmaf(w, Kc[base], kf);
        vf = fmaf(w, Vc[base], vf);
      }
    vfs[k][o] = vf;
    float p = wred_sum(qv * kf);
    if (lane == 0) lgs[wid][k] = p * 0.125f;
  }
  __syncthreads();
  float a[NK];
  float mx = -1e30f;
#pragma unroll
  for (int k = 0; k < NK; ++k) { a[k] = lgs[wid][k]; mx = fmaxf(mx, a[k]); }
  float sum = 0.f;
#pragma unroll
  for (int k = 0; k < NK; ++k) { a[k] = expf(a[k] - mx); sum += a[k]; }
  float outv = 0.f;
#pragma unroll
  for (int k = 0; k < NK; ++k) outv = fmaf(a[k] / sum, vfs[k][o], outv);
  attn_out[((size_t)b * NN + n) * NC + o] = outv;
}

extern "C" void kernel_launch(void* const* d_in, const int* in_sizes, int n_in,
                              void* d_out, int out_size, void* d_ws, size_t ws_size,
                              hipStream_t stream) {
  (void)in_sizes; (void)n_in; (void)out_size; (void)ws_size;
  const float* q     = (const float*)d_in[0];
  const float* q_pos = (const float*)d_in[1];
  const float* v     = (const float*)d_in[2];
  const float* v_pos = (const float*)d_in[3];
  const float* Wq    = (const float*)d_in[4];
  const float* Wk    = (const float*)d_in[5];
  const float* Wv    = (const float*)d_in[6];
  const float* Wvoff = (const float*)d_in[7];
  const float* Woff1 = (const float*)d_in[8];
  const float* boff1 = (const float*)d_in[9];
  const float* ln_g  = (const float*)d_in[10];
  const float* ln_b  = (const float*)d_in[11];
  const float* Woff2 = (const float*)d_in[12];
  const float* Wproj = (const float*)d_in[13];
  const float* bproj = (const float*)d_in[14];
  float* out = (float*)d_out;

  char* p = (char*)d_ws;
  auto alloc_f = [&](size_t n) { float* r = (float*)p; p += n * sizeof(float); return r; };
  auto alloc_i = [&](size_t n) { int* r = (int*)p; p += n * sizeof(int); return r; };

  float* qp        = alloc_f((size_t)NB * NN * NC);
  float* qcontrib  = alloc_f((size_t)NG * NB * NN * NC);
  float* vcontrib  = alloc_f((size_t)NG * NB * NM * NC);
  float* KcT       = alloc_f((size_t)NG * NB * NM * NC);
  float* VcT       = alloc_f((size_t)NG * NB * NM * NC);
  float* Wt_all    = alloc_f((size_t)WT_ALL_FLOATS);
  float* Wcomb_t   = alloc_f((size_t)NG * NC * NC);
  float* w3        = alloc_f((size_t)NB * NG * NN * NK * 3);
  int* knn_idx     = alloc_i((size_t)NB * NN * NK);
  int* idx3        = alloc_i((size_t)NB * NG * NN * NK * 3);
  float* attn_out  = vcontrib;  // vcontrib dead after mlp3nn_k; reuse

  transpose_all_k<<<dim3(576, 7), 256, 0, stream>>>(Wq, Woff1, Wk, Wv, Wproj, Wt_all);
  wcomb_k<<<dim3(NC, NG), NC, 0, stream>>>(Woff1, Wvoff, Wcomb_t);

  qproj_k<<<NB * NN / 16, 384, 0, stream>>>(q, Wt_all, qp, qcontrib);
  knn2_k<<<NB * (NN / 4), 256, 0, stream>>>(q_pos, v_pos, knn_idx);
  vproj_k<<<NB * NM / 16, 384, 0, stream>>>(v, Wcomb_t, Wt_all, vcontrib, KcT, VcT);

  mlp3nn_k<<<NB * NG * NN * NK / 4, 256, 0, stream>>>(vcontrib, qcontrib, boff1, ln_g, ln_b,
                                                      Woff2, knn_idx, v_pos, idx3, w3);
  attn_k<<<NB * NN, NC, 0, stream>>>(qp, KcT, VcT, idx3, w3, attn_out);
  linear2_k<<<NB * NN / 16, 384, 0, stream>>>(attn_out, NC, Wt_all + OFF_WPROJ, bproj, out);
}

// Round 5
// 474.985 us; speedup vs baseline: 2.2740x; 1.1439x over previous
//
#include <hip/hip_runtime.h>
#include <math.h>

#define NB 4
#define NN 1024
#define NM 1024
#define NC 384
#define NK 10
#define NG 2
#define NGC 192
#define NH 6

#define GSZ ((size_t)NB * NM * NC)  // per-g table size (floats)

// Wt_all layout (floats)
#define OFF_WQ 0
#define OFF_W1B 147456
#define OFF_WK0 221184
#define OFF_WK1 294912
#define OFF_WV0 368640
#define OFF_WV1 442368
#define OFF_WPROJ 516096
#define WT_ALL_FLOATS 663552

__device__ __forceinline__ float wred_sum(float v) {
#pragma unroll
  for (int m = 32; m >= 1; m >>= 1) v += __shfl_xor(v, m, 64);
  return v;
}

// lexicographic (d, m) min across 64 lanes; ties -> lower m (matches top_k)
__device__ __forceinline__ void wred_argmin(float& d, int& m) {
#pragma unroll
  for (int off = 32; off >= 1; off >>= 1) {
    float od = __shfl_xor(d, off, 64);
    int om = __shfl_xor(m, off, 64);
    if (od < d || (od == d && om < m)) { d = od; m = om; }
  }
}

// all 7 weight transposes in one launch; blockIdx.y = job
__global__ void transpose_all_k(const float* __restrict__ Wq, const float* __restrict__ Woff1,
                                const float* __restrict__ Wk, const float* __restrict__ Wv,
                                const float* __restrict__ Wproj, float* __restrict__ Wt_all) {
  const float* W;
  int i0, icount, doff;
  switch (blockIdx.y) {
    case 0: W = Wq;    i0 = 0;   icount = NC;  doff = OFF_WQ;    break;
    case 1: W = Woff1; i0 = NGC; icount = NGC; doff = OFF_W1B;   break;
    case 2: W = Wk;    i0 = 0;   icount = NGC; doff = OFF_WK0;   break;
    case 3: W = Wk;    i0 = NGC; icount = NGC; doff = OFF_WK1;   break;
    case 4: W = Wv;    i0 = 0;   icount = NGC; doff = OFF_WV0;   break;
    case 5: W = Wv;    i0 = NGC; icount = NGC; doff = OFF_WV1;   break;
    default: W = Wproj; i0 = 0;  icount = NC;  doff = OFF_WPROJ; break;
  }
  int id = blockIdx.x * 256 + threadIdx.x;
  if (id >= icount * NC) return;
  int o = id % NC;
  int i = id / NC;
  Wt_all[doff + (size_t)i * NC + o] = W[(size_t)o * NC + i0 + i];
}

// Wcomb_t[g][i][o] = sum_j Woff1[o][j] * Wvoff[g*192+j][i]   (j < 192)
__global__ void wcomb_k(const float* __restrict__ Woff1, const float* __restrict__ Wvoff,
                        float* __restrict__ Wcomb_t) {
  int o = blockIdx.x;
  int g = blockIdx.y;
  int i = threadIdx.x;
  __shared__ float w1[NGC];
  if (i < NGC) w1[i] = Woff1[(size_t)o * NC + i];
  __syncthreads();
  float acc = 0.f;
#pragma unroll 4
  for (int j = 0; j < NGC; ++j)
    acc = fmaf(w1[j], Wvoff[(size_t)(g * NGC + j) * NC + i], acc);
  Wcomb_t[((size_t)g * NC + i) * NC + o] = acc;
}

// generic 16-row 4x4 register-blocked GEMM; blockIdx.y = job:
//   xoff = xoff0 + job*xoff_stride; Wt += job*wstride; Y += job*ystride
__global__ __launch_bounds__(384) void gemm16_k(const float* __restrict__ X, int IN, int xoff0,
                                                int xoff_stride, const float* __restrict__ Wt0,
                                                size_t wstride, const float* __restrict__ bias,
                                                float* __restrict__ Y0, size_t ystride) {
  __shared__ __align__(16) float xs[NC][20];
  int tid = threadIdx.x;
  int og = tid % 96, rg = tid / 96;
  int r0 = blockIdx.x * 16;
  int job = blockIdx.y;
  int xoff = xoff0 + job * xoff_stride;
  const float* Wt = Wt0 + (size_t)job * wstride;
  float* Y = Y0 + (size_t)job * ystride;
  for (int t = tid; t < 16 * IN; t += 384) {
    int r = t / IN, kk = t % IN;
    xs[kk][r] = X[(size_t)(r0 + r) * NC + xoff + kk];
  }
  __syncthreads();
  float acc[4][4];
#pragma unroll
  for (int i = 0; i < 4; ++i)
#pragma unroll
    for (int j = 0; j < 4; ++j) acc[i][j] = 0.f;
  int o = og * 4;
#pragma unroll 4
  for (int kk = 0; kk < IN; ++kk) {
    float4 w4 = *(const float4*)&Wt[(size_t)kk * NC + o];
    float4 x4 = *(const float4*)&xs[kk][rg * 4];
    float xr[4] = {x4.x, x4.y, x4.z, x4.w};
    float wr[4] = {w4.x, w4.y, w4.z, w4.w};
#pragma unroll
    for (int ri = 0; ri < 4; ++ri)
#pragma unroll
      for (int oi = 0; oi < 4; ++oi) acc[ri][oi] = fmaf(xr[ri], wr[oi], acc[ri][oi]);
  }
  float4 bv = make_float4(0.f, 0.f, 0.f, 0.f);
  if (bias) bv = *(const float4*)&bias[o];
#pragma unroll
  for (int ri = 0; ri < 4; ++ri) {
    float4 ov;
    ov.x = acc[ri][0] + bv.x;
    ov.y = acc[ri][1] + bv.y;
    ov.z = acc[ri][2] + bv.z;
    ov.w = acc[ri][3] + bv.w;
    *(float4*)&Y[(size_t)(r0 + rg * 4 + ri) * NC + o] = ov;
  }
}

// v projections, blockIdx.y = job in {vcontrib g0,g1 (IN=384, Wcomb), Kc g0/g1, Vc g0/g1 (IN=192)}
__global__ __launch_bounds__(384) void vproj_k(const float* __restrict__ v,
                                               const float* __restrict__ Wcomb_t,
                                               const float* __restrict__ Wt_all,
                                               float* __restrict__ vcontrib,
                                               float* __restrict__ KcT,
                                               float* __restrict__ VcT) {
  __shared__ __align__(16) float xs[NC][20];
  int tid = threadIdx.x;
  int og = tid % 96, rg = tid / 96;
  int r0 = blockIdx.x * 16;
  int job = blockIdx.y;
  const float* Wt;
  float* Y;
  int IN, xoff;
  switch (job) {
    case 0: Wt = Wcomb_t;                 Y = vcontrib;       IN = NC;  xoff = 0;   break;
    case 1: Wt = Wcomb_t + (size_t)NC * NC; Y = vcontrib + GSZ; IN = NC;  xoff = 0;   break;
    case 2: Wt = Wt_all + OFF_WK0;        Y = KcT;            IN = NGC; xoff = 0;   break;
    case 3: Wt = Wt_all + OFF_WK1;        Y = KcT + GSZ;      IN = NGC; xoff = NGC; break;
    case 4: Wt = Wt_all + OFF_WV0;        Y = VcT;            IN = NGC; xoff = 0;   break;
    default: Wt = Wt_all + OFF_WV1;       Y = VcT + GSZ;      IN = NGC; xoff = NGC; break;
  }
  for (int t = tid; t < 16 * IN; t += 384) {
    int r = t / IN, kk = t % IN;
    xs[kk][r] = v[(size_t)(r0 + r) * NC + xoff + kk];
  }
  __syncthreads();
  float acc[4][4];
#pragma unroll
  for (int i = 0; i < 4; ++i)
#pragma unroll
    for (int j = 0; j < 4; ++j) acc[i][j] = 0.f;
  int o = og * 4;
#pragma unroll 4
  for (int kk = 0; kk < IN; ++kk) {
    float4 w4 = *(const float4*)&Wt[(size_t)kk * NC + o];
    float4 x4 = *(const float4*)&xs[kk][rg * 4];
    float xr[4] = {x4.x, x4.y, x4.z, x4.w};
    float wr[4] = {w4.x, w4.y, w4.z, w4.w};
#pragma unroll
    for (int ri = 0; ri < 4; ++ri)
#pragma unroll
      for (int oi = 0; oi < 4; ++oi) acc[ri][oi] = fmaf(xr[ri], wr[oi], acc[ri][oi]);
  }
#pragma unroll
  for (int ri = 0; ri < 4; ++ri)
    *(float4*)&Y[(size_t)(r0 + rg * 4 + ri) * NC + o] =
        make_float4(acc[ri][0], acc[ri][1], acc[ri][2], acc[ri][3]);
}

// wave-per-query KNN: lane scans 16 candidates -> register top-10 -> argmin-merge
__global__ __launch_bounds__(256) void knn2_k(const float* __restrict__ q_pos,
                                              const float* __restrict__ v_pos,
                                              int* __restrict__ knn_idx) {
  __shared__ float px[NM], py[NM], pz[NM], ss[NM];
  int tid = threadIdx.x, lane = tid & 63, wid = tid >> 6;
  int b = blockIdx.x / (NN / 4);
  int n = (blockIdx.x % (NN / 4)) * 4 + wid;
  for (int t = tid; t < NM; t += 256) {
    float x = v_pos[((size_t)b * NM + t) * 3 + 0];
    float y = v_pos[((size_t)b * NM + t) * 3 + 1];
    float z = v_pos[((size_t)b * NM + t) * 3 + 2];
    px[t] = x; py[t] = y; pz[t] = z;
    ss[t] = x * x + y * y + z * z;
  }
  __syncthreads();
  float qx = q_pos[((size_t)b * NN + n) * 3 + 0];
  float qy = q_pos[((size_t)b * NN + n) * 3 + 1];
  float qz = q_pos[((size_t)b * NN + n) * 3 + 2];
  float qq = qx * qx + qy * qy + qz * qz;
  float bd[NK];
  int bi[NK];
#pragma unroll
  for (int j = 0; j < NK; ++j) { bd[j] = 1e30f; bi[j] = 0x7fffffff; }
#pragma unroll
  for (int t = 0; t < NM / 64; ++t) {
    int m = t * 64 + lane;
    float d = qq + ss[m] - 2.f * (qx * px[m] + qy * py[m] + qz * pz[m]);
    if (d < bd[NK - 1]) {
#pragma unroll
      for (int j = NK - 1; j > 0; --j) {
        if (d < bd[j - 1]) { bd[j] = bd[j - 1]; bi[j] = bi[j - 1]; }
        else if (d < bd[j]) { bd[j] = d; bi[j] = m; }
      }
      if (d < bd[0]) { bd[0] = d; bi[0] = m; }
    }
  }
  size_t base = ((size_t)b * NN + n) * NK;
#pragma unroll
  for (int round = 0; round < NK; ++round) {
    float dh = bd[0];
    int mh = bi[0];
    wred_argmin(dh, mh);
    if (lane == 0) knn_idx[base + round] = mh;
    if (bi[0] == mh) {
#pragma unroll
      for (int j = 0; j < NK - 1; ++j) { bd[j] = bd[j + 1]; bi[j] = bi[j + 1]; }
      bd[NK - 1] = 1e30f; bi[NK - 1] = 0x7fffffff;
    }
  }
}

// fused MLP + three_nn: one wave per (b,g,n,k) row
__global__ __launch_bounds__(256) void mlp3nn_k(
    const float* __restrict__ vcontrib, const float* __restrict__ qcontrib,
    const float* __restrict__ boff1, const float* __restrict__ ln_g,
    const float* __restrict__ ln_b, const float* __restrict__ Woff2,
    const int* __restrict__ knn_idx, const float* __restrict__ v_pos,
    int* __restrict__ idx3, float* __restrict__ w3) {
  __shared__ float px[NM], py[NM], pz[NM], ss[NM];
  int tid = threadIdx.x, lane = tid & 63, wid = tid >> 6;
  int r = blockIdx.x * 4 + wid;
  int b = (blockIdx.x * 4) / (NK * NN * NG);
  for (int t = tid; t < NM; t += 256) {
    float x = v_pos[((size_t)b * NM + t) * 3 + 0];
    float y = v_pos[((size_t)b * NM + t) * 3 + 1];
    float z = v_pos[((size_t)b * NM + t) * 3 + 2];
    px[t] = x; py[t] = y; pz[t] = z;
    ss[t] = x * x + y * y + z * z;
  }
  __syncthreads();
  int k = r % NK;
  int n = (r / NK) % NN;
  int g = (r / (NK * NN)) % NG;
  int m = knn_idx[((size_t)b * NN + n) * NK + k];
  const float* vc = vcontrib + ((size_t)(g * NB + b) * NM + m) * NC;
  const float* qc = qcontrib + ((size_t)(g * NB + b) * NN + n) * NC;
  float h[6];
  float s = 0.f, s2 = 0.f;
#pragma unroll
  for (int j = 0; j < 6; ++j) {
    int c = j * 64 + lane;
    float x = vc[c] + qc[c] + boff1[c];
    h[j] = x; s += x; s2 += x * x;
  }
  s = wred_sum(s);
  s2 = wred_sum(s2);
  float mean = s * (1.f / NC);
  float var = s2 * (1.f / NC) - mean * mean;
  float inv = 1.f / sqrtf(var + 1e-5f);
  float p0 = 0.f, p1 = 0.f, p2 = 0.f;
#pragma unroll
  for (int j = 0; j < 6; ++j) {
    int c = j * 64 + lane;
    float x = (h[j] - mean) * inv * ln_g[c] + ln_b[c];
    x = 0.5f * x * (1.f + erff(x * 0.70710678118654752f));
    p0 = fmaf(x, Woff2[0 * NC + c], p0);
    p1 = fmaf(x, Woff2[1 * NC + c], p1);
    p2 = fmaf(x, Woff2[2 * NC + c], p2);
  }
  p0 = wred_sum(p0);
  p1 = wred_sum(p1);
  p2 = wred_sum(p2);
  float sx = px[m] + tanhf(p0);
  float sy = py[m] + tanhf(p1);
  float sz = pz[m] + tanhf(p2);
  float qq2 = sx * sx + sy * sy + sz * sz;
  float d0v = 1e30f, d1v = 1e30f, d2v = 1e30f;
  int i0v = 0x7fffffff, i1v = 0x7fffffff, i2v = 0x7fffffff;
#pragma unroll
  for (int t = 0; t < NM / 64; ++t) {
    int m2 = t * 64 + lane;
    float d = qq2 + ss[m2] - 2.f * (sx * px[m2] + sy * py[m2] + sz * pz[m2]);
    if (d < d2v) {
      d2v = d; i2v = m2;
      if (d2v < d1v) { float td = d1v; d1v = d2v; d2v = td; int ti = i1v; i1v = i2v; i2v = ti; }
      if (d1v < d0v) { float td = d0v; d0v = d1v; d1v = td; int ti = i0v; i0v = i1v; i1v = ti; }
    }
  }
  float rd[3];
  int rm[3];
#pragma unroll
  for (int round = 0; round < 3; ++round) {
    float dh = d0v;
    int mh = i0v;
    wred_argmin(dh, mh);
    rd[round] = dh; rm[round] = mh;
    if (i0v == mh) {
      d0v = d1v; i0v = i1v;
      d1v = d2v; i1v = i2v;
      d2v = 1e30f; i2v = 0x7fffffff;
    }
  }
  if (lane == 0) {
    float e0 = 1.f / (sqrtf(fmaxf(rd[0], 0.f)) + 1e-8f);
    float e1 = 1.f / (sqrtf(fmaxf(rd[1], 0.f)) + 1e-8f);
    float e2 = 1.f / (sqrtf(fmaxf(rd[2], 0.f)) + 1e-8f);
    float sw = e0 + e1 + e2;
    idx3[(size_t)r * 3 + 0] = rm[0]; w3[(size_t)r * 3 + 0] = e0 / sw;
    idx3[(size_t)r * 3 + 1] = rm[1]; w3[(size_t)r * 3 + 1] = e1 / sw;
    idx3[(size_t)r * 3 + 2] = rm[2]; w3[(size_t)r * 3 + 2] = e2 / sw;
  }
}

// one block per (b,n): kf/vf via 6-term gathered sums from Kc/Vc tables, then 6-head 10-way attention
__global__ __launch_bounds__(NC) void attn_k(const float* __restrict__ qp,
                                             const float* __restrict__ Kc,
                                             const float* __restrict__ Vc,
                                             const int* __restrict__ idx3,
                                             const float* __restrict__ w3,
                                             float* __restrict__ attn_out) {
  __shared__ float vfs[NK][NC];
  __shared__ float lgs[NH][NK];
  __shared__ int il[NG][NK][3];
  __shared__ float wl[NG][NK][3];
  int o = threadIdx.x;
  int lane = o & 63, wid = o >> 6;
  int b = blockIdx.x / NN;
  int n = blockIdx.x % NN;
  if (o < NG * NK * 3) {
    int g = o / (NK * 3), k = (o / 3) % NK, j = o % 3;
    size_t rr = (((size_t)(b * NG + g) * NN + n) * NK + k) * 3 + j;
    il[g][k][j] = idx3[rr];
    wl[g][k][j] = w3[rr];
  }
  __syncthreads();
  float qv = qp[((size_t)b * NN + n) * NC + o];
  for (int k = 0; k < NK; ++k) {
    float kf = 0.f, vf = 0.f;
#pragma unroll
    for (int g = 0; g < NG; ++g)
#pragma unroll
      for (int j = 0; j < 3; ++j) {
        int m = il[g][k][j];
        float w = wl[g][k][j];
        size_t base = ((size_t)(g * NB + b) * NM + m) * NC + o;
        kf = fmaf(w, Kc[base], kf);
        vf = fmaf(w, Vc[base], vf);
      }
    vfs[k][o] = vf;
    float p = wred_sum(qv * kf);
    if (lane == 0) lgs[wid][k] = p * 0.125f;
  }
  __syncthreads();
  float a[NK];
  float mx = -1e30f;
#pragma unroll
  for (int k = 0; k < NK; ++k) { a[k] = lgs[wid][k]; mx = fmaxf(mx, a[k]); }
  float sum = 0.f;
#pragma unroll
  for (int k = 0; k < NK; ++k) { a[k] = expf(a[k] - mx); sum += a[k]; }
  float outv = 0.f;
#pragma unroll
  for (int k = 0; k < NK; ++k) outv = fmaf(a[k] / sum, vfs[k][o], outv);
  attn_out[((size_t)b * NN + n) * NC + o] = outv;
}

extern "C" void kernel_launch(void* const* d_in, const int* in_sizes, int n_in,
                              void* d_out, int out_size, void* d_ws, size_t ws_size,
                              hipStream_t stream) {
  (void)in_sizes; (void)n_in; (void)out_size; (void)ws_size;
  const float* q     = (const float*)d_in[0];
  const float* q_pos = (const float*)d_in[1];
  const float* v     = (const float*)d_in[2];
  const float* v_pos = (const float*)d_in[3];
  const float* Wq    = (const float*)d_in[4];
  const float* Wk    = (const float*)d_in[5];
  const float* Wv    = (const float*)d_in[6];
  const float* Wvoff = (const float*)d_in[7];
  const float* Woff1 = (const float*)d_in[8];
  const float* boff1 = (const float*)d_in[9];
  const float* ln_g  = (const float*)d_in[10];
  const float* ln_b  = (const float*)d_in[11];
  const float* Woff2 = (const float*)d_in[12];
  const float* Wproj = (const float*)d_in[13];
  const float* bproj = (const float*)d_in[14];
  float* out = (float*)d_out;

  char* p = (char*)d_ws;
  auto alloc_f = [&](size_t n) { float* r = (float*)p; p += n * sizeof(float); return r; };
  auto alloc_i = [&](size_t n) { int* r = (int*)p; p += n * sizeof(int); return r; };

  float* qp        = alloc_f((size_t)NB * NN * NC);
  float* qcontrib  = alloc_f((size_t)NG * NB * NN * NC);
  float* vcontrib  = alloc_f((size_t)NG * NB * NM * NC);
  float* KcT       = alloc_f((size_t)NG * NB * NM * NC);
  float* VcT       = alloc_f((size_t)NG * NB * NM * NC);
  float* Wt_all    = alloc_f((size_t)WT_ALL_FLOATS);
  float* Wcomb_t   = alloc_f((size_t)NG * NC * NC);
  float* w3        = alloc_f((size_t)NB * NG * NN * NK * 3);
  int* knn_idx     = alloc_i((size_t)NB * NN * NK);
  int* idx3        = alloc_i((size_t)NB * NG * NN * NK * 3);
  float* attn_out  = vcontrib;  // vcontrib dead after mlp3nn_k; reuse

  transpose_all_k<<<dim3(576, 7), 256, 0, stream>>>(Wq, Woff1, Wk, Wv, Wproj, Wt_all);
  wcomb_k<<<dim3(NC, NG), NC, 0, stream>>>(Woff1, Wvoff, Wcomb_t);

  // qp = q @ Wq^T
  gemm16_k<<<dim3(NB * NN / 16, 1), 384, 0, stream>>>(q, NC, 0, 0, Wt_all + OFF_WQ, 0, nullptr,
                                                      qp, 0);
  knn2_k<<<NB * (NN / 4), 256, 0, stream>>>(q_pos, v_pos, knn_idx);
  // qcontrib[g] = qp[:, g*192:(g+1)*192] @ W1b   (same W1b for both g)
  gemm16_k<<<dim3(NB * NN / 16, 2), 384, 0, stream>>>(qp, NGC, 0, NGC, Wt_all + OFF_W1B, 0,
                                                      nullptr, qcontrib, (size_t)NB * NN * NC);
  // 6 v-side projections, one job per blockIdx.y
  vproj_k<<<dim3(NB * NM / 16, 6), 384, 0, stream>>>(v, Wcomb_t, Wt_all, vcontrib, KcT, VcT);

  mlp3nn_k<<<NB * NG * NN * NK / 4, 256, 0, stream>>>(vcontrib, qcontrib, boff1, ln_g, ln_b,
                                                      Woff2, knn_idx, v_pos, idx3, w3);
  attn_k<<<NB * NN, NC, 0, stream>>>(qp, KcT, VcT, idx3, w3, attn_out);
  gemm16_k<<<dim3(NB * NN / 16, 1), 384, 0, stream>>>(attn_out, NC, 0, 0, Wt_all + OFF_WPROJ, 0,
                                                      bproj, out, 0);
}